// Round 1
// baseline (1004.915 us; speedup 1.0000x reference)
//
#include <hip/hip_runtime.h>

#define BN_EPS 1e-5f

// ---------------- degree / norm ----------------

__global__ __launch_bounds__(256) void k_deg_init(float* deg, int n) {
    int i = blockIdx.x * 256 + threadIdx.x;
    if (i < n) deg[i] = 1.0f;   // self-loop
}

__global__ __launch_bounds__(256) void k_deg_count(const int* __restrict__ dst, float* deg, int e) {
    int i = blockIdx.x * 256 + threadIdx.x;
    if (i < e) atomicAdd(&deg[dst[i]], 1.0f);
}

__global__ __launch_bounds__(256) void k_dinv(float* deg, int n) {
    int i = blockIdx.x * 256 + threadIdx.x;
    if (i < n) deg[i] = rsqrtf(deg[i]);   // deg >= 1 always
}

__global__ __launch_bounds__(256) void k_norm(const int* __restrict__ src, const int* __restrict__ dst,
                                              const float* __restrict__ dinv, float* __restrict__ norm, int e) {
    int i = blockIdx.x * 256 + threadIdx.x;
    if (i < e) norm[i] = dinv[src[i]] * dinv[dst[i]];
}

// ---------------- dense linear (weights staged in LDS) ----------------
// block = 256 threads = (256/FOUT) rows x FOUT cols

template<int FIN, int FOUT, bool RELU, bool BIAS>
__global__ __launch_bounds__(256) void k_linear(const float* __restrict__ X, const float* __restrict__ W,
                                                const float* __restrict__ bias, float* __restrict__ Y, int n) {
    constexpr int ROWS = 256 / FOUT;
    __shared__ float Ws[FIN * FOUT];
    __shared__ float Xs[ROWS][FIN];
    for (int i = threadIdx.x; i < FIN * FOUT; i += 256) Ws[i] = W[i];

    const int col = threadIdx.x % FOUT;
    const int rlane = threadIdx.x / FOUT;

    for (int r0 = blockIdx.x * ROWS; r0 < n; r0 += gridDim.x * ROWS) {
        __syncthreads();
        for (int i = threadIdx.x; i < ROWS * FIN; i += 256) {
            int rr = i / FIN, cc = i % FIN;
            int row = r0 + rr;
            Xs[rr][cc] = (row < n) ? X[(size_t)row * FIN + cc] : 0.0f;
        }
        __syncthreads();
        int row = r0 + rlane;
        if (row < n) {
            float acc = BIAS ? bias[col] : 0.0f;
            #pragma unroll 8
            for (int k = 0; k < FIN; ++k) acc += Xs[rlane][k] * Ws[k * FOUT + col];
            if (RELU) acc = fmaxf(acc, 0.0f);
            Y[(size_t)row * FOUT + col] = acc;
        }
    }
}

// ---------------- GCN scatter ----------------

// Z[i,:] = T[i,:] * dinv[i]^2 + bias   (self-loop contribution + conv bias)
template<int F>
__global__ __launch_bounds__(256) void k_self_bias(const float* __restrict__ T, const float* __restrict__ dinv,
                                                   const float* __restrict__ bias, float* __restrict__ Z, int n) {
    size_t tot = (size_t)n * F;
    for (size_t idx = (size_t)blockIdx.x * 256 + threadIdx.x; idx < tot; idx += (size_t)gridDim.x * 256) {
        int row = (int)(idx / F);
        int c = (int)(idx % F);
        float dv = dinv[row];
        Z[idx] = T[idx] * dv * dv + bias[c];
    }
}

// Z[dst,:] += T[src,:] * norm[e]
template<int F>
__global__ __launch_bounds__(256) void k_scatter(const int* __restrict__ src, const int* __restrict__ dst,
                                                 const float* __restrict__ norm, const float* __restrict__ T,
                                                 float* __restrict__ Z, int e) {
    size_t tot = (size_t)e * F;
    for (size_t idx = (size_t)blockIdx.x * 256 + threadIdx.x; idx < tot; idx += (size_t)gridDim.x * 256) {
        int ed = (int)(idx / F);
        int c = (int)(idx % F);
        int s = src[ed], d = dst[ed];
        atomicAdd(&Z[(size_t)d * F + c], T[(size_t)s * F + c] * norm[ed]);
    }
}

// ---------------- batchnorm ----------------

// S[0..F-1] = sum, S[F..2F-1] = sumsq (S pre-zeroed)
template<int F>
__global__ __launch_bounds__(256) void k_bn_stats(const float* __restrict__ Z, float* __restrict__ S, int n) {
    constexpr int ROWS = 256 / F;
    const int col = threadIdx.x % F;
    const int rlane = threadIdx.x / F;
    float s1 = 0.f, s2 = 0.f;
    for (int r = blockIdx.x * ROWS + rlane; r < n; r += gridDim.x * ROWS) {
        float v = Z[(size_t)r * F + col];
        s1 += v; s2 += v * v;
    }
    __shared__ float sh1[256], sh2[256];
    sh1[threadIdx.x] = s1; sh2[threadIdx.x] = s2;
    __syncthreads();
    if (rlane == 0) {
        #pragma unroll
        for (int r = 1; r < ROWS; ++r) { s1 += sh1[r * F + col]; s2 += sh2[r * F + col]; }
        atomicAdd(&S[col], s1);
        atomicAdd(&S[F + col], s2);
    }
}

template<int F>
__global__ __launch_bounds__(256) void k_bn_apply(float* __restrict__ Z, const float* __restrict__ S,
                                                  const float* __restrict__ g, const float* __restrict__ b, int n) {
    const float inv_n = 1.0f / (float)n;
    size_t tot = (size_t)n * F;
    for (size_t idx = (size_t)blockIdx.x * 256 + threadIdx.x; idx < tot; idx += (size_t)gridDim.x * 256) {
        int c = (int)(idx % F);
        float mu = S[c] * inv_n;
        float var = S[F + c] * inv_n - mu * mu;
        float inv = rsqrtf(var + BN_EPS);
        float v = (Z[idx] - mu) * inv * g[c] + b[c];
        Z[idx] = fmaxf(v, 0.0f);
    }
}

// ---------------- fc2 + log_softmax ----------------

__global__ __launch_bounds__(256) void k_fc2_lsm(const float* __restrict__ Hin, const float* __restrict__ W,
                                                 const float* __restrict__ bias, float* __restrict__ out, int n) {
    __shared__ float Ws[256];
    __shared__ float bs[16];
    Ws[threadIdx.x] = W[threadIdx.x];
    if (threadIdx.x < 16) bs[threadIdx.x] = bias[threadIdx.x];
    __syncthreads();
    for (int row = blockIdx.x * 256 + threadIdx.x; row < n; row += gridDim.x * 256) {
        float h[16];
        const float4* hp = (const float4*)(Hin + (size_t)row * 16);
        float4 h4;
        #pragma unroll
        for (int q = 0; q < 4; ++q) {
            h4 = hp[q];
            h[q * 4 + 0] = h4.x; h[q * 4 + 1] = h4.y; h[q * 4 + 2] = h4.z; h[q * 4 + 3] = h4.w;
        }
        float o[16];
        #pragma unroll
        for (int c = 0; c < 16; ++c) {
            float acc = bs[c];
            #pragma unroll
            for (int k = 0; k < 16; ++k) acc += h[k] * Ws[k * 16 + c];
            o[c] = acc;
        }
        float m = o[0];
        #pragma unroll
        for (int c = 1; c < 16; ++c) m = fmaxf(m, o[c]);
        float ssum = 0.f;
        #pragma unroll
        for (int c = 0; c < 16; ++c) ssum += expf(o[c] - m);
        float lse = m + logf(ssum);
        float4* op = (float4*)(out + (size_t)row * 16);
        #pragma unroll
        for (int q = 0; q < 4; ++q) {
            float4 w4;
            w4.x = o[q * 4 + 0] - lse; w4.y = o[q * 4 + 1] - lse;
            w4.z = o[q * 4 + 2] - lse; w4.w = o[q * 4 + 3] - lse;
            op[q] = w4;
        }
    }
}

// ---------------- launch ----------------

extern "C" void kernel_launch(void* const* d_in, const int* in_sizes, int n_in,
                              void* d_out, int out_size, void* d_ws, size_t ws_size,
                              hipStream_t stream) {
    const float* x      = (const float*)d_in[0];
    const int*   ei     = (const int*)d_in[1];
    const float* fc1_w  = (const float*)d_in[2];
    const float* fc1_b  = (const float*)d_in[3];
    const float* conv_w[3] = { (const float*)d_in[4],  (const float*)d_in[8],  (const float*)d_in[12] };
    const float* conv_b[3] = { (const float*)d_in[5],  (const float*)d_in[9],  (const float*)d_in[13] };
    const float* bn_g[3]   = { (const float*)d_in[6],  (const float*)d_in[10], (const float*)d_in[14] };
    const float* bn_b[3]   = { (const float*)d_in[7],  (const float*)d_in[11], (const float*)d_in[15] };
    const float* fc2_w  = (const float*)d_in[16];
    const float* fc2_b  = (const float*)d_in[17];

    const int n = in_sizes[0] / 128;
    const int e = in_sizes[1] / 2;
    const int* src = ei;
    const int* dst = ei + e;

    char* ws = (char*)d_ws;
    float* A    = (float*)ws;                                // n*64 f32
    float* B    = (float*)(ws + (size_t)n * 64 * 4);         // n*64 f32
    float* dinv = (float*)(ws + (size_t)n * 64 * 4 * 2);     // n   (deg -> dinv in place)
    float* norm = dinv + n;                                  // e
    float* stats = norm + e;                                 // 128

    const int gN   = (n + 255) / 256;
    const int gE   = (e + 255) / 256;
    const int gEl  = 4096;    // elementwise grid (n*64 = 6.4M, grid-stride)
    const int gSc  = 8192;    // scatter grid (e*64 = 80M, grid-stride)
    const int gLin = 2048;    // linear grid
    const int gSt  = 1024;    // bn-stats grid

    // degrees + norms (shared by all 3 conv layers)
    k_deg_init<<<gN, 256, 0, stream>>>(dinv, n);
    k_deg_count<<<gE, 256, 0, stream>>>(dst, dinv, e);
    k_dinv<<<gN, 256, 0, stream>>>(dinv, n);
    k_norm<<<gE, 256, 0, stream>>>(src, dst, dinv, norm, e);

    // fc1 + relu : A = relu(x @ W1 + b1)
    k_linear<128, 64, true, true><<<gLin, 256, 0, stream>>>(x, fc1_w, fc1_b, A, n);

    // conv0, conv1 (64 -> 64)
    for (int l = 0; l < 2; ++l) {
        k_linear<64, 64, false, false><<<gLin, 256, 0, stream>>>(A, conv_w[l], nullptr, B, n);
        k_self_bias<64><<<gEl, 256, 0, stream>>>(B, dinv, conv_b[l], A, n);
        k_scatter<64><<<gSc, 256, 0, stream>>>(src, dst, norm, B, A, e);
        hipMemsetAsync(stats, 0, 128 * sizeof(float), stream);
        k_bn_stats<64><<<gSt, 256, 0, stream>>>(A, stats, n);
        k_bn_apply<64><<<gEl, 256, 0, stream>>>(A, stats, bn_g[l], bn_b[l], n);
    }

    // conv2 (64 -> 16)
    k_linear<64, 16, false, false><<<gLin, 256, 0, stream>>>(A, conv_w[2], nullptr, B, n);
    k_self_bias<16><<<gEl, 256, 0, stream>>>(B, dinv, conv_b[2], A, n);
    k_scatter<16><<<gSc, 256, 0, stream>>>(src, dst, norm, B, A, e);
    hipMemsetAsync(stats, 0, 128 * sizeof(float), stream);
    k_bn_stats<16><<<gSt, 256, 0, stream>>>(A, stats, n);
    k_bn_apply<16><<<gEl, 256, 0, stream>>>(A, stats, bn_b[2] ? bn_g[2] : bn_g[2], bn_b[2], n);

    // fc2 + log_softmax -> d_out
    k_fc2_lsm<<<gLin, 256, 0, stream>>>(A, fc2_w, fc2_b, (float*)d_out, n);
}

// Round 2
// 673.656 us; speedup vs baseline: 1.4917x; 1.4917x over previous
//
#include <hip/hip_runtime.h>

#define BN_EPS 1e-5f

// ---------------- degree / dinv ----------------

__global__ __launch_bounds__(256) void k_deg_count(const int* __restrict__ dst, int* deg, int e) {
    int i = blockIdx.x * 256 + threadIdx.x;
    if (i < e) atomicAdd(&deg[dst[i]], 1);
}

__global__ __launch_bounds__(256) void k_dinv(const int* __restrict__ deg, float* __restrict__ dinv, int n) {
    int i = blockIdx.x * 256 + threadIdx.x;
    if (i < n) dinv[i] = rsqrtf((float)deg[i] + 1.0f);   // +1 = self-loop
}

// ---------------- exclusive scan (CSR offsets) ----------------

__global__ __launch_bounds__(256) void k_scan1(const int* __restrict__ deg, int* __restrict__ off,
                                               int* __restrict__ bsum, int n) {
    __shared__ int sh[256];
    int i = blockIdx.x * 256 + threadIdx.x;
    int v = (i < n) ? deg[i] : 0;
    sh[threadIdx.x] = v;
    __syncthreads();
    #pragma unroll
    for (int d = 1; d < 256; d <<= 1) {
        int t = (threadIdx.x >= d) ? sh[threadIdx.x - d] : 0;
        __syncthreads();
        sh[threadIdx.x] += t;
        __syncthreads();
    }
    if (i < n) off[i] = sh[threadIdx.x] - v;             // exclusive within block
    if (threadIdx.x == 255) bsum[blockIdx.x] = sh[255];  // block total
}

__global__ __launch_bounds__(512) void k_scan2(int* bsum, int nb) {
    __shared__ int sh[512];
    int v = (threadIdx.x < nb) ? bsum[threadIdx.x] : 0;
    sh[threadIdx.x] = v;
    __syncthreads();
    #pragma unroll
    for (int d = 1; d < 512; d <<= 1) {
        int t = (threadIdx.x >= d) ? sh[threadIdx.x - d] : 0;
        __syncthreads();
        sh[threadIdx.x] += t;
        __syncthreads();
    }
    if (threadIdx.x < nb) bsum[threadIdx.x] = sh[threadIdx.x] - v;  // exclusive
}

__global__ __launch_bounds__(256) void k_scan3(int* __restrict__ off, const int* __restrict__ bsum,
                                               int* __restrict__ cnt, int n, int e) {
    int i = blockIdx.x * 256 + threadIdx.x;
    if (i < n) { off[i] += bsum[blockIdx.x]; cnt[i] = 0; }
    if (i == 0) off[n] = e;
}

__global__ __launch_bounds__(256) void k_fill(const int* __restrict__ src, const int* __restrict__ dst,
                                              const int* __restrict__ off, int* __restrict__ cnt,
                                              int* __restrict__ esrc, int e) {
    int i = blockIdx.x * 256 + threadIdx.x;
    if (i < e) {
        int d = dst[i];
        int slot = off[d] + atomicAdd(&cnt[d], 1);
        esrc[slot] = src[i];
    }
}

// ---------------- dense linear (weights in LDS, optional fused BN+relu on input) ----------------
// block = 256 threads = (256/FOUT) rows x FOUT cols

template<int FIN, int FOUT, bool RELU, bool BIAS, bool BNIN>
__global__ __launch_bounds__(256) void k_linear(const float* __restrict__ X, const float* __restrict__ W,
                                                const float* __restrict__ bias, float* __restrict__ Y,
                                                const float* __restrict__ S, const float* __restrict__ bng,
                                                const float* __restrict__ bnb, float inv_n, int n) {
    constexpr int ROWS = 256 / FOUT;
    __shared__ float Ws[FIN * FOUT];
    __shared__ float Xs[ROWS][FIN];
    __shared__ float sc[BNIN ? FIN : 1], sf[BNIN ? FIN : 1];
    for (int i = threadIdx.x; i < FIN * FOUT; i += 256) Ws[i] = W[i];
    if (BNIN && threadIdx.x < FIN) {
        int c = threadIdx.x;
        float mu = S[c] * inv_n;
        float var = S[FIN + c] * inv_n - mu * mu;
        float is = rsqrtf(var + BN_EPS) * bng[c];
        sc[c] = is;
        sf[c] = bnb[c] - mu * is;
    }

    const int col = threadIdx.x % FOUT;
    const int rlane = threadIdx.x / FOUT;

    for (int r0 = blockIdx.x * ROWS; r0 < n; r0 += gridDim.x * ROWS) {
        __syncthreads();
        for (int i = threadIdx.x; i < ROWS * FIN; i += 256) {
            int rr = i / FIN, cc = i % FIN;
            int row = r0 + rr;
            float v = (row < n) ? X[(size_t)row * FIN + cc] : 0.0f;
            if (BNIN) v = fmaxf(fmaf(v, sc[cc], sf[cc]), 0.0f);
            Xs[rr][cc] = v;
        }
        __syncthreads();
        int row = r0 + rlane;
        if (row < n) {
            float acc = BIAS ? bias[col] : 0.0f;
            #pragma unroll 8
            for (int k = 0; k < FIN; ++k) acc += Xs[rlane][k] * Ws[k * FOUT + col];
            if (RELU) acc = fmaxf(acc, 0.0f);
            Y[(size_t)row * FOUT + col] = acc;
        }
    }
}

// ---------------- GCN accumulate (CSR gather) + fused self-loop/bias + BN partial stats ----------------

// Z[d,:] = dinv[d] * ( T[d,:]*dinv[d] + sum_{s in N(d)} T[s,:]*dinv[s] ) + bias
// F == 64: one node per wave (lane = col)
__global__ __launch_bounds__(256) void k_accum64(const float* __restrict__ T, const int* __restrict__ esrc,
                                                 const int* __restrict__ off, const float* __restrict__ dinv,
                                                 const float* __restrict__ bias, float* __restrict__ Z,
                                                 float* __restrict__ S, int n) {
    const int lane = threadIdx.x & 63;
    const int wid = threadIdx.x >> 6;
    float s1 = 0.f, s2 = 0.f;
    const float bcol = bias[lane];
    for (int d = blockIdx.x * 4 + wid; d < n; d += gridDim.x * 4) {
        int o0 = off[d], o1 = off[d + 1];
        float dv = dinv[d];
        float acc = T[(size_t)d * 64 + lane] * dv;
        int o = o0;
        for (; o + 1 < o1; o += 2) {
            int sA = esrc[o], sB = esrc[o + 1];
            float wA = dinv[sA], wB = dinv[sB];
            acc = fmaf(T[(size_t)sA * 64 + lane], wA, acc);
            acc = fmaf(T[(size_t)sB * 64 + lane], wB, acc);
        }
        if (o < o1) {
            int sA = esrc[o];
            acc = fmaf(T[(size_t)sA * 64 + lane], dinv[sA], acc);
        }
        acc = fmaf(acc, dv, bcol);
        Z[(size_t)d * 64 + lane] = acc;
        s1 += acc;
        s2 += acc * acc;
    }
    __shared__ float sh1[256], sh2[256];
    sh1[threadIdx.x] = s1;
    sh2[threadIdx.x] = s2;
    __syncthreads();
    if (wid == 0) {
        #pragma unroll
        for (int w = 1; w < 4; ++w) { s1 += sh1[w * 64 + lane]; s2 += sh2[w * 64 + lane]; }
        atomicAdd(&S[lane], s1);
        atomicAdd(&S[64 + lane], s2);
    }
}

// F == 16: four nodes per wave (col = lane&15, sub = lane>>4)
__global__ __launch_bounds__(256) void k_accum16(const float* __restrict__ T, const int* __restrict__ esrc,
                                                 const int* __restrict__ off, const float* __restrict__ dinv,
                                                 const float* __restrict__ bias, float* __restrict__ Z,
                                                 float* __restrict__ S, int n) {
    const int col = threadIdx.x & 15;
    const int grp = threadIdx.x >> 4;   // 0..15 node-group within block
    float s1 = 0.f, s2 = 0.f;
    const float bcol = bias[col];
    for (int d = blockIdx.x * 16 + grp; d < n; d += gridDim.x * 16) {
        int o0 = off[d], o1 = off[d + 1];
        float dv = dinv[d];
        float acc = T[(size_t)d * 16 + col] * dv;
        int o = o0;
        for (; o + 1 < o1; o += 2) {
            int sA = esrc[o], sB = esrc[o + 1];
            float wA = dinv[sA], wB = dinv[sB];
            acc = fmaf(T[(size_t)sA * 16 + col], wA, acc);
            acc = fmaf(T[(size_t)sB * 16 + col], wB, acc);
        }
        if (o < o1) {
            int sA = esrc[o];
            acc = fmaf(T[(size_t)sA * 16 + col], dinv[sA], acc);
        }
        acc = fmaf(acc, dv, bcol);
        Z[(size_t)d * 16 + col] = acc;
        s1 += acc;
        s2 += acc * acc;
    }
    __shared__ float sh1[256], sh2[256];
    sh1[threadIdx.x] = s1;
    sh2[threadIdx.x] = s2;
    __syncthreads();
    if (threadIdx.x < 16) {
        #pragma unroll
        for (int r = 1; r < 16; ++r) { s1 += sh1[r * 16 + col]; s2 += sh2[r * 16 + col]; }
        atomicAdd(&S[col], s1);
        atomicAdd(&S[16 + col], s2);
    }
}

// ---------------- fc2 + log_softmax (fused BN+relu input) ----------------

__global__ __launch_bounds__(256) void k_fc2_lsm(const float* __restrict__ Hin, const float* __restrict__ W,
                                                 const float* __restrict__ bias, const float* __restrict__ S,
                                                 const float* __restrict__ bng, const float* __restrict__ bnb,
                                                 float inv_n, float* __restrict__ out, int n) {
    __shared__ float Ws[256];
    __shared__ float bs[16], sc[16], sf[16];
    Ws[threadIdx.x] = W[threadIdx.x];
    if (threadIdx.x < 16) {
        int c = threadIdx.x;
        bs[c] = bias[c];
        float mu = S[c] * inv_n;
        float var = S[16 + c] * inv_n - mu * mu;
        float is = rsqrtf(var + BN_EPS) * bng[c];
        sc[c] = is;
        sf[c] = bnb[c] - mu * is;
    }
    __syncthreads();
    for (int row = blockIdx.x * 256 + threadIdx.x; row < n; row += gridDim.x * 256) {
        float h[16];
        const float4* hp = (const float4*)(Hin + (size_t)row * 16);
        #pragma unroll
        for (int q = 0; q < 4; ++q) {
            float4 h4 = hp[q];
            h[q * 4 + 0] = h4.x; h[q * 4 + 1] = h4.y; h[q * 4 + 2] = h4.z; h[q * 4 + 3] = h4.w;
        }
        #pragma unroll
        for (int k = 0; k < 16; ++k) h[k] = fmaxf(fmaf(h[k], sc[k], sf[k]), 0.0f);
        float o[16];
        #pragma unroll
        for (int c = 0; c < 16; ++c) {
            float acc = bs[c];
            #pragma unroll
            for (int k = 0; k < 16; ++k) acc += h[k] * Ws[k * 16 + c];
            o[c] = acc;
        }
        float m = o[0];
        #pragma unroll
        for (int c = 1; c < 16; ++c) m = fmaxf(m, o[c]);
        float ssum = 0.f;
        #pragma unroll
        for (int c = 0; c < 16; ++c) ssum += expf(o[c] - m);
        float lse = m + logf(ssum);
        float4* op = (float4*)(out + (size_t)row * 16);
        #pragma unroll
        for (int q = 0; q < 4; ++q) {
            float4 w4;
            w4.x = o[q * 4 + 0] - lse; w4.y = o[q * 4 + 1] - lse;
            w4.z = o[q * 4 + 2] - lse; w4.w = o[q * 4 + 3] - lse;
            op[q] = w4;
        }
    }
}

// ---------------- launch ----------------

extern "C" void kernel_launch(void* const* d_in, const int* in_sizes, int n_in,
                              void* d_out, int out_size, void* d_ws, size_t ws_size,
                              hipStream_t stream) {
    const float* x      = (const float*)d_in[0];
    const int*   ei     = (const int*)d_in[1];
    const float* fc1_w  = (const float*)d_in[2];
    const float* fc1_b  = (const float*)d_in[3];
    const float* conv_w[3] = { (const float*)d_in[4],  (const float*)d_in[8],  (const float*)d_in[12] };
    const float* conv_b[3] = { (const float*)d_in[5],  (const float*)d_in[9],  (const float*)d_in[13] };
    const float* bn_g[3]   = { (const float*)d_in[6],  (const float*)d_in[10], (const float*)d_in[14] };
    const float* bn_b[3]   = { (const float*)d_in[7],  (const float*)d_in[11], (const float*)d_in[15] };
    const float* fc2_w  = (const float*)d_in[16];
    const float* fc2_b  = (const float*)d_in[17];

    const int n = in_sizes[0] / 128;
    const int e = in_sizes[1] / 2;
    const int* src = ei;
    const int* dst = ei + e;
    const float inv_n = 1.0f / (float)n;

    // workspace layout (all 4-byte types)
    float* A    = (float*)d_ws;            // n*64
    float* B    = A + (size_t)n * 64;      // n*64
    float* dinv = B + (size_t)n * 64;      // n
    int*   deg  = (int*)(dinv + n);        // n  (doubles as cnt after scan)
    int*   off  = deg + n;                 // n+1
    int*   esrc = off + n + 1;             // e
    float* stats = (float*)(esrc + e);     // 3 * 128
    int*   bsum = (int*)(stats + 384);     // scan block sums (<=512)

    const int gN  = (n + 255) / 256;
    const int gE  = (e + 255) / 256;
    const int gLin = 2048;
    const int gAcc = 2048;

    float* st[3] = { stats, stats + 128, stats + 256 };

    // CSR build (shared by all 3 conv layers)
    hipMemsetAsync(deg, 0, (size_t)n * sizeof(int), stream);
    hipMemsetAsync(stats, 0, 384 * sizeof(float), stream);
    k_deg_count<<<gE, 256, 0, stream>>>(dst, deg, e);
    k_dinv<<<gN, 256, 0, stream>>>(deg, dinv, n);
    k_scan1<<<gN, 256, 0, stream>>>(deg, off, bsum, n);
    k_scan2<<<1, 512, 0, stream>>>(bsum, gN);
    k_scan3<<<gN, 256, 0, stream>>>(off, bsum, deg /*cnt*/, n, e);
    k_fill<<<gE, 256, 0, stream>>>(src, dst, off, deg /*cnt*/, esrc, e);

    // fc1 + relu : A = relu(x @ W1 + b1)
    k_linear<128, 64, true, true, false><<<gLin, 256, 0, stream>>>(
        x, fc1_w, fc1_b, A, nullptr, nullptr, nullptr, 0.f, n);

    // conv0: B = A @ W0 ; A = gcn(B) (+bias, +stats0)
    k_linear<64, 64, false, false, false><<<gLin, 256, 0, stream>>>(
        A, conv_w[0], nullptr, B, nullptr, nullptr, nullptr, 0.f, n);
    k_accum64<<<gAcc, 256, 0, stream>>>(B, esrc, off, dinv, conv_b[0], A, st[0], n);

    // conv1: B = bnrelu(A) @ W1 ; A = gcn(B) (+bias, +stats1)
    k_linear<64, 64, false, false, true><<<gLin, 256, 0, stream>>>(
        A, conv_w[1], nullptr, B, st[0], bn_g[0], bn_b[0], inv_n, n);
    k_accum64<<<gAcc, 256, 0, stream>>>(B, esrc, off, dinv, conv_b[1], A, st[1], n);

    // conv2: B = bnrelu(A) @ W2 (64->16) ; A = gcn(B) (+bias, +stats2)
    k_linear<64, 16, false, false, true><<<gLin, 256, 0, stream>>>(
        A, conv_w[2], nullptr, B, st[1], bn_g[1], bn_b[1], inv_n, n);
    k_accum16<<<gAcc, 256, 0, stream>>>(B, esrc, off, dinv, conv_b[2], A, st[2], n);

    // fc2 + log_softmax (bn+relu fused on input) -> d_out
    k_fc2_lsm<<<gLin, 256, 0, stream>>>(A, fc2_w, fc2_b, st[2], bn_g[2], bn_b[2], inv_n, (float*)d_out, n);
}